// Round 11
// baseline (268.095 us; speedup 1.0000x reference)
//
#include <hip/hip_runtime.h>
#include <hip/hip_bf16.h>

typedef __attribute__((ext_vector_type(8))) short bf16x8;
typedef __attribute__((ext_vector_type(4))) float f32x4;

#define NH 16
#define DM 1024
#define HD 64
#define CSEQ 2048
#define MROWS 8192   // B*C
#define NBH 64       // B*NH

static __device__ __forceinline__ unsigned short f2bf(float f) {
  __hip_bfloat16 h = __float2bfloat16(f);
  return *reinterpret_cast<unsigned short*>(&h);
}

static __device__ __forceinline__ short bf_qscale(short s) {
  // fold attn scale (1/8) and log2(e) into Q: S*0.125*1.4427 -> exp2 domain
  unsigned u = ((unsigned)(unsigned short)s) << 16;
  float f = __builtin_bit_cast(float, u) * 0.18033688f;
  return (short)f2bf(f);
}

static __device__ __forceinline__ void gload_lds16(const void* g, void* l) {
  __builtin_amdgcn_global_load_lds(
      (const __attribute__((address_space(1))) unsigned int*)g,
      (__attribute__((address_space(3))) unsigned int*)l, 16, 0, 0);
}

// ---------------- cast fp32 -> bf16 (vectorized x4) ----------------
__global__ __launch_bounds__(256) void cast_f32_bf16(const float* __restrict__ in,
                                                     unsigned short* __restrict__ out,
                                                     int n4) {
  int stride = gridDim.x * blockDim.x;
  for (int i = blockIdx.x * blockDim.x + threadIdx.x; i < n4; i += stride) {
    float4 v = ((const float4*)in)[i];
    ushort4 o;
    o.x = f2bf(v.x); o.y = f2bf(v.y); o.z = f2bf(v.z); o.w = f2bf(v.w);
    ((ushort4*)out)[i] = o;
  }
}

// ---------------- transpose + cast: src[K][N] fp32 -> dst[N][K] bf16 ----------------
__global__ __launch_bounds__(256) void transpose_cast(const float* __restrict__ src,
                                                      unsigned short* __restrict__ dst,
                                                      int K, int N) {
  __shared__ float tile[32][33];
  int tx = threadIdx.x, ty = threadIdx.y;
  int n0 = blockIdx.x * 32, k0 = blockIdx.y * 32;
  #pragma unroll
  for (int i = 0; i < 32; i += 8)
    tile[ty + i][tx] = src[(size_t)(k0 + ty + i) * N + n0 + tx];
  __syncthreads();
  #pragma unroll
  for (int i = 0; i < 32; i += 8)
    dst[(size_t)(n0 + ty + i) * K + k0 + tx] = f2bf(tile[tx][ty + i]);
}

// ---------------- shared helpers ----------------
template<int CNT>
static __device__ __forceinline__ void ld_frags(const char* base, int r0, int cx, int g,
                                                bf16x8 (*out)[2]) {
  #pragma unroll
  for (int i = 0; i < CNT; i++) {
    int row = r0 + i * 16 + cx;
    #pragma unroll
    for (int kc = 0; kc < 2; kc++)
      out[i][kc] = *(const bf16x8*)(base + row * 128 + ((((kc << 2) | g) ^ (row & 7)) << 4));
  }
}

#define BARR() __builtin_amdgcn_s_barrier()
#define LGKM0() asm volatile("s_waitcnt lgkmcnt(0)" ::: "memory")
#define VMCNT8() asm volatile("s_waitcnt vmcnt(8)" ::: "memory")
#define VMCNT0() asm volatile("s_waitcnt vmcnt(0)" ::: "memory")
#define PRIO1() __builtin_amdgcn_s_setprio(1)
#define PRIO0() __builtin_amdgcn_s_setprio(0)

static __device__ __forceinline__ void mfma_all(const bf16x8 af[4][2], const bf16x8 bfr[4][2],
                                                f32x4 acc[4][4]) {
  #pragma unroll
  for (int kc = 0; kc < 2; kc++)
    #pragma unroll
    for (int mi = 0; mi < 4; mi++)
      #pragma unroll
      for (int ni = 0; ni < 4; ni++)
        acc[mi][ni] = __builtin_amdgcn_mfma_f32_16x16x32_bf16(
            af[mi][kc], bfr[ni][kc], acc[mi][ni], 0, 0, 0);
}

// ---------------- QKV scatter epilogue element ----------------
static __device__ __forceinline__ void qkv_scatter(unsigned short* __restrict__ outQKV,
                                                   int rr, int col, float v) {
  int which = col >> 10, rem = col & 1023;
  int h = rem >> 6, d = rem & 63;
  int b = rr >> 11, cq = rr & 2047;
  if (which == 2) {
    // V: store transposed + kappa-permuted (pure within-32 permutation)
    int pos = (cq & ~31) + (((cq >> 2) & 3) << 3) + (((cq >> 4) & 1) << 2) + (cq & 3);
    outQKV[((size_t)2 * NBH + b * NH + h) * (CSEQ * HD) + (size_t)d * CSEQ + pos] = f2bf(v);
  } else {
    outQKV[((size_t)which * NBH + b * NH + h) * (CSEQ * HD) + (size_t)cq * HD + d] = f2bf(v);
  }
}

// ===================== 128x128 bf16 GEMM, SINGLE-buffer, 4 blocks/CU (QKV) =====================
// Occupancy experiment: 32KB LDS (no dbuf) + VGPR 88 <= 128 -> 4 blocks/CU
// (16 waves/CU, vs R9's 2 blocks).  Within a block the tile is fully serial
// (stage -> vmcnt0 -> reads+MFMA -> barrier, ~500cyc exposed drain/tile), but
// 4 naturally-staggered co-resident blocks cover each other's drains (m114
// inter-block overlap); binding term becomes LDS BW (~750 cyc/tile -> ~2x
// headroom over R9's measured 2090).  Grid 1536: greedy dispatch, small tail.
__global__ __launch_bounds__(256, 4) void gemm_qkv(const unsigned short* __restrict__ A,
                                                   const unsigned short* __restrict__ BT,
                                                   const float* __restrict__ bias,
                                                   unsigned short* __restrict__ outQKV,
                                                   int N, int K) {
  __shared__ char sA[16384];   // [128 rows][64 k] bf16, rows 128B, slot^(row&7) swizzle
  __shared__ char sB[16384];
  int tid = threadIdx.x;
  int w = tid >> 6, l = tid & 63, g = l >> 4, cx = l & 15;
  int wm = (w >> 1) * 64, wn = (w & 1) * 64;

  // XCD-aware bijective swizzle (nwg % 8 == 0: 1536)
  int nwgx = gridDim.x;
  int nwg = nwgx * gridDim.y;
  int gid = blockIdx.y * nwgx + blockIdx.x;
  int swz = (gid & 7) * (nwg >> 3) + (gid >> 3);
  int bm = (swz / nwgx) * 128, bn = (swz % nwgx) * 128;

  const unsigned short* Ap[4];
  const unsigned short* Bp[4];
  #pragma unroll
  for (int i = 0; i < 4; i++) {
    int c = tid + i * 256;
    int ar = c >> 3, as = ((c & 7) ^ (ar & 7)) * 8;
    Ap[i] = A + (size_t)(bm + ar) * K + as;
    Bp[i] = BT + (size_t)(bn + ar) * K + as;
  }

  #define STAGE_S(t) do { int ko_ = (t) << 6;                   \
      gload_lds16(Ap[0] + ko_, sA + (tid)       * 16);          \
      gload_lds16(Ap[1] + ko_, sA + (tid + 256) * 16);          \
      gload_lds16(Ap[2] + ko_, sA + (tid + 512) * 16);          \
      gload_lds16(Ap[3] + ko_, sA + (tid + 768) * 16);          \
      gload_lds16(Bp[0] + ko_, sB + (tid)       * 16);          \
      gload_lds16(Bp[1] + ko_, sB + (tid + 256) * 16);          \
      gload_lds16(Bp[2] + ko_, sB + (tid + 512) * 16);          \
      gload_lds16(Bp[3] + ko_, sB + (tid + 768) * 16);          \
    } while (0)

  f32x4 acc[4][4];
  #pragma unroll
  for (int i = 0; i < 4; i++)
    #pragma unroll
    for (int j = 0; j < 4; j++) acc[i][j] = (f32x4){0.f, 0.f, 0.f, 0.f};

  int NT = K >> 6;

  for (int t = 0; t < NT; t++) {
    STAGE_S(t);
    VMCNT0();
    BARR();   // tile t fully in LDS

    bf16x8 af[4][2], bfr[4][2];
    ld_frags<4>(sA, wm, cx, g, af);
    ld_frags<4>(sB, wn, cx, g, bfr);
    LGKM0();

    PRIO1(); mfma_all(af, bfr, acc); PRIO0();

    BARR();   // all waves' reads complete -> next stage may overwrite
  }

  // epilogue: C/D layout row=(l>>4)*4+r (m-side), col=l&15 (n-side)
  #pragma unroll
  for (int mi = 0; mi < 4; mi++) {
    #pragma unroll
    for (int ni = 0; ni < 4; ni++) {
      int col = bn + wn + ni * 16 + cx;
      float bv = bias[col];
      int row0 = bm + wm + mi * 16 + g * 4;
      #pragma unroll
      for (int r = 0; r < 4; r++)
        qkv_scatter(outQKV, row0 + r, col, acc[mi][ni][r] + bv);
    }
  }
  #undef STAGE_S
}

// ===================== 128x128 bf16 GEMM, 2 blocks/CU, 2 barriers/tile (proj) =====================
// R9-verified structure.
__global__ __launch_bounds__(256, 2) void gemm128d(const unsigned short* __restrict__ A,
                                                   const unsigned short* __restrict__ BT,
                                                   const float* __restrict__ bias,
                                                   float* __restrict__ outF,
                                                   int N, int K) {
  __shared__ char sA[2][16384];   // [128 rows][64 k] bf16, rows 128B, slot^(row&7) swizzle
  __shared__ char sB[2][16384];
  int tid = threadIdx.x;
  int w = tid >> 6, l = tid & 63, g = l >> 4, cx = l & 15;
  int wm = (w >> 1) * 64, wn = (w & 1) * 64;

  // XCD-aware bijective swizzle (nwg % 8 == 0: 512)
  int nwgx = gridDim.x;
  int nwg = nwgx * gridDim.y;
  int gid = blockIdx.y * nwgx + blockIdx.x;
  int swz = (gid & 7) * (nwg >> 3) + (gid >> 3);
  int bm = (swz / nwgx) * 128, bn = (swz % nwgx) * 128;

  const unsigned short* Ap[4];
  const unsigned short* Bp[4];
  #pragma unroll
  for (int i = 0; i < 4; i++) {
    int c = tid + i * 256;
    int ar = c >> 3, as = ((c & 7) ^ (ar & 7)) * 8;
    Ap[i] = A + (size_t)(bm + ar) * K + as;
    Bp[i] = BT + (size_t)(bn + ar) * K + as;
  }

  #define STAGE_AB(t, buf) do { int ko_ = (t) << 6;                 \
      gload_lds16(Ap[0] + ko_, sA[buf] + (tid)       * 16);         \
      gload_lds16(Ap[1] + ko_, sA[buf] + (tid + 256) * 16);         \
      gload_lds16(Ap[2] + ko_, sA[buf] + (tid + 512) * 16);         \
      gload_lds16(Ap[3] + ko_, sA[buf] + (tid + 768) * 16);         \
      gload_lds16(Bp[0] + ko_, sB[buf] + (tid)       * 16);         \
      gload_lds16(Bp[1] + ko_, sB[buf] + (tid + 256) * 16);         \
      gload_lds16(Bp[2] + ko_, sB[buf] + (tid + 512) * 16);         \
      gload_lds16(Bp[3] + ko_, sB[buf] + (tid + 768) * 16);         \
    } while (0)

  f32x4 acc[4][4];
  #pragma unroll
  for (int i = 0; i < 4; i++)
    #pragma unroll
    for (int j = 0; j < 4; j++) acc[i][j] = (f32x4){0.f, 0.f, 0.f, 0.f};

  int NT = K >> 6;

  STAGE_AB(0, 0);
  STAGE_AB(1, 1);
  VMCNT8();
  BARR();

  int cur = 0;
  for (int t = 0; t < NT; t++) {
    const char* Ac = sA[cur];
    const char* Bc = sB[cur];
    bool h1 = (t + 1) < NT, h2 = (t + 2) < NT;
    bf16x8 af[4][2], bfr[4][2];

    ld_frags<4>(Ac, wm, cx, g, af);
    ld_frags<4>(Bc, wn, cx, g, bfr);
    LGKM0();
    BARR();   // every wave's frags now in regs -> buffer cur is dead

    if (h2) STAGE_AB(t + 2, cur);

    PRIO1(); mfma_all(af, bfr, acc); PRIO0();

    if (h2)      { VMCNT8(); }
    else if (h1) { VMCNT0(); }
    BARR();
    cur ^= 1;
  }

  #pragma unroll
  for (int mi = 0; mi < 4; mi++) {
    #pragma unroll
    for (int ni = 0; ni < 4; ni++) {
      int col = bn + wn + ni * 16 + cx;
      float bv = bias[col];
      int row0 = bm + wm + mi * 16 + g * 4;
      #pragma unroll
      for (int r = 0; r < 4; r++)
        outF[(size_t)(row0 + r) * N + col] = acc[mi][ni][r] + bv;
    }
  }
  #undef STAGE_AB
}

// ---------------- flash attention (causal), swapped-QK^T, register-P ----------------
// R9-verified: 8 waves x 16 q-rows (QBLK=128), KVBLK=128, dbuf, one barrier/iter,
// XCD-aware remap, exp2 softmax, defer-max, DMA staging, ones-MFMA denominator.
__global__ __launch_bounds__(512, 4) void attn_kernel(const unsigned short* __restrict__ Qb,
                                                      const unsigned short* __restrict__ Kb,
                                                      const unsigned short* __restrict__ VTb,
                                                      unsigned short* __restrict__ O) {
  __shared__ char sKb[2][16384]; // K [128 k][64 d] bf16: slot sp of row holds d-slot sp^(row&7)
  __shared__ char sVt[2][16384]; // V^T [64 d][128 pos] bf16: slot sp of row d holds pos-slot sp^(d&7)
  int tid = threadIdx.x;
  int w = tid >> 6, l = tid & 63, g = l >> 4, cx = l & 15;
  int gid = blockIdx.x;
  int bh = ((gid >> 7) << 3) | (gid & 7);
  int qt = 15 - ((gid >> 3) & 15);

  const unsigned short* Qp  = Qb  + (size_t)bh * CSEQ * HD;
  const unsigned short* Kp  = Kb  + (size_t)bh * CSEQ * HD;
  const unsigned short* VTp = VTb + (size_t)bh * CSEQ * HD;  // [64 d][2048 k']

  int qrow = qt * 128 + w * 16 + cx;
  bf16x8 qf[2];
  qf[0] = *(const bf16x8*)(Qp + (size_t)qrow * HD + g * 8);
  qf[1] = *(const bf16x8*)(Qp + (size_t)qrow * HD + 32 + g * 8);
  #pragma unroll
  for (int kc = 0; kc < 2; kc++)
    #pragma unroll
    for (int j = 0; j < 8; j++) qf[kc][j] = bf_qscale(qf[kc][j]);

  bf16x8 vones;
  #pragma unroll
  for (int j = 0; j < 8; j++) vones[j] = (short)0x3F80;   // bf16 1.0

  f32x4 o[4], osum;
  #pragma unroll
  for (int nf2 = 0; nf2 < 4; nf2++) o[nf2] = (f32x4){0.f, 0.f, 0.f, 0.f};
  osum = (f32x4){0.f, 0.f, 0.f, 0.f};
  float mrow = -INFINITY;

  int c0 = tid, c1 = tid + 512;
  int krow0 = c0 >> 3, ksl0 = (c0 & 7) ^ (krow0 & 7);
  int krow1 = c1 >> 3, ksl1 = (c1 & 7) ^ (krow1 & 7);
  int vd0 = c0 >> 4, vsl0 = (c0 & 15) ^ (vd0 & 7);
  int vd1 = c1 >> 4, vsl1 = (c1 & 15) ^ (vd1 & 7);
  const unsigned short* Ksrc0 = Kp + (size_t)krow0 * HD + ksl0 * 8;   // += kt*8192
  const unsigned short* Ksrc1 = Kp + (size_t)krow1 * HD + ksl1 * 8;
  const unsigned short* Vsrc0 = VTp + (size_t)vd0 * CSEQ + vsl0 * 8;  // += kt*128
  const unsigned short* Vsrc1 = VTp + (size_t)vd1 * CSEQ + vsl1 * 8;

  gload_lds16(Ksrc0, sKb[0] + c0 * 16);
  gload_lds16(Ksrc1, sKb[0] + c1 * 16);
  gload_lds16(Vsrc0, sVt[0] + c0 * 16);
  gload_lds16(Vsrc1, sVt[0] + c1 * 16);
  __syncthreads();
  int cur = 0;

  for (int kt = 0; kt <= qt; kt++) {
    if (kt < qt) {
      size_t ko = (size_t)(kt + 1) * 128 * HD;
      size_t vo = (size_t)(kt + 1) * 128;
      gload_lds16(Ksrc0 + ko, sKb[cur ^ 1] + c0 * 16);
      gload_lds16(Ksrc1 + ko, sKb[cur ^ 1] + c1 * 16);
      gload_lds16(Vsrc0 + vo, sVt[cur ^ 1] + c0 * 16);
      gload_lds16(Vsrc1 + vo, sVt[cur ^ 1] + c1 * 16);
    }
    const char* Kc = sKb[cur];
    const char* Vc = sVt[cur];

    f32x4 sacc[8];
    #pragma unroll
    for (int nf = 0; nf < 8; nf++) sacc[nf] = (f32x4){0.f, 0.f, 0.f, 0.f};
    __builtin_amdgcn_s_setprio(1);
    #pragma unroll
    for (int kc = 0; kc < 2; kc++) {
      #pragma unroll
      for (int nf = 0; nf < 8; nf++) {
        int row = nf * 16 + cx;
        bf16x8 kf = *(const bf16x8*)(Kc + row * 128 + ((((kc << 2) | g) ^ (row & 7)) << 4));
        sacc[nf] = __builtin_amdgcn_mfma_f32_16x16x32_bf16(kf, qf[kc], sacc[nf], 0, 0, 0);
      }
    }
    __builtin_amdgcn_s_setprio(0);

    if (kt == qt) {
      #pragma unroll
      for (int nf = 0; nf < 8; nf++)
        #pragma unroll
        for (int r = 0; r < 4; r++)
          if (nf * 16 + 4 * g + r > w * 16 + cx) sacc[nf][r] = -INFINITY;
    }
    float m8[8];
    #pragma unroll
    for (int nf = 0; nf < 8; nf++)
      m8[nf] = fmaxf(fmaxf(sacc[nf][0], sacc[nf][1]), fmaxf(sacc[nf][2], sacc[nf][3]));
    float mx = fmaxf(fmaxf(fmaxf(m8[0], m8[1]), fmaxf(m8[2], m8[3])),
                     fmaxf(fmaxf(m8[4], m8[5]), fmaxf(m8[6], m8[7])));
    mx = fmaxf(mx, __shfl_xor(mx, 16));
    mx = fmaxf(mx, __shfl_xor(mx, 32));

    if (!__all(mx - mrow <= 8.f)) {
      float mnew = fmaxf(mrow, mx);
      float alpha = __builtin_amdgcn_exp2f(mrow - mnew);
      mrow = mnew;
      #pragma unroll
      for (int r = 0; r < 4; r++) {
        float ar = __shfl(alpha, (l & 48) | ((l >> 2) & 12) | r);
        #pragma unroll
        for (int nf2 = 0; nf2 < 4; nf2++) o[nf2][r] *= ar;
        osum[r] *= ar;
      }
    }
    #pragma unroll
    for (int nf = 0; nf < 8; nf++)
      #pragma unroll
      for (int r = 0; r < 4; r++)
        sacc[nf][r] = __builtin_amdgcn_exp2f(sacc[nf][r] - mrow);

    bf16x8 pa[4];
    #pragma unroll
    for (int kc = 0; kc < 4; kc++) {
      #pragma unroll
      for (int j = 0; j < 4; j++) {
        pa[kc][j]     = (short)f2bf(sacc[2 * kc][j]);
        pa[kc][j + 4] = (short)f2bf(sacc[2 * kc + 1][j]);
      }
    }

    __builtin_amdgcn_s_setprio(1);
    #pragma unroll
    for (int kc = 0; kc < 4; kc++) {
      #pragma unroll
      for (int nf2 = 0; nf2 < 4; nf2++) {
        int d = nf2 * 16 + cx;
        bf16x8 vf = *(const bf16x8*)(Vc + ((d * 256 + (((kc << 2) | g) << 4)) ^ ((d & 7) << 4)));
        o[nf2] = __builtin_amdgcn_mfma_f32_16x16x32_bf16(pa[kc], vf, o[nf2], 0, 0, 0);
      }
      osum = __builtin_amdgcn_mfma_f32_16x16x32_bf16(pa[kc], vones, osum, 0, 0, 0);
    }
    __builtin_amdgcn_s_setprio(0);

    if (kt < qt) {
      __syncthreads();
      cur ^= 1;
    }
  }

  int b = bh >> 4, h = bh & 15;
  #pragma unroll
  for (int r = 0; r < 4; r++) {
    float inv = 1.0f / osum[r];
    int q = qt * 128 + w * 16 + 4 * g + r;
    size_t base = ((size_t)(b * CSEQ + q)) * DM + h * HD;
    #pragma unroll
    for (int nf2 = 0; nf2 < 4; nf2++)
      O[base + nf2 * 16 + cx] = f2bf(o[nf2][r] * inv);
  }
}

// ---------------- launch ----------------
extern "C" void kernel_launch(void* const* d_in, const int* in_sizes, int n_in,
                              void* d_out, int out_size, void* d_ws, size_t ws_size,
                              hipStream_t stream) {
  const float* x    = (const float*)d_in[0];
  const float* Wqkv = (const float*)d_in[1];
  const float* bqkv = (const float*)d_in[2];
  const float* Wo   = (const float*)d_in[3];
  const float* bo   = (const float*)d_in[4];
  float* out = (float*)d_out;

  unsigned short* ws = (unsigned short*)d_ws;
  const size_t XB_OFF    = 0;                     // x bf16 [8192][1024]
  const size_t WQKVT_OFF = 8388608;               // Wqkv^T bf16 [3072][1024]
  const size_t WOT_OFF   = WQKVT_OFF + 3145728;   // Wo^T bf16 [1024][1024]
  const size_t QKV_OFF   = WOT_OFF + 1048576;     // Q,K [bh][k][d]; V^T [bh][d][k']
  const size_t ATT_OFF   = QKV_OFF + 3 * 8388608; // att out bf16 [8192][1024]

  unsigned short* xb    = ws + XB_OFF;
  unsigned short* wqkvT = ws + WQKVT_OFF;
  unsigned short* woT   = ws + WOT_OFF;
  unsigned short* qkv   = ws + QKV_OFF;
  unsigned short* att   = ws + ATT_OFF;

  cast_f32_bf16<<<2048, 256, 0, stream>>>(x, xb, (MROWS * DM) / 4);
  transpose_cast<<<dim3(3 * DM / 32, DM / 32), dim3(32, 8), 0, stream>>>(Wqkv, wqkvT, DM, 3 * DM);
  transpose_cast<<<dim3(DM / 32, DM / 32), dim3(32, 8), 0, stream>>>(Wo, woT, DM, DM);

  // QKV: single-buffer 128x128, 4 blocks/CU occupancy experiment (1536 blocks)
  gemm_qkv<<<dim3(3 * DM / 128, MROWS / 128), 256, 0, stream>>>(
      xb, wqkvT, bqkv, qkv, 3 * DM, DM);

  attn_kernel<<<dim3(1024), 512, 0, stream>>>(
      qkv, qkv + 8388608, qkv + 16777216, att);

  // proj: R9-verified dbuf 2-blocks/CU (512 blocks, 1 exact round)
  gemm128d<<<dim3(DM / 128, MROWS / 128), 256, 0, stream>>>(
      att, woT, bo, out, DM, DM);
}

// Round 12
// 186.619 us; speedup vs baseline: 1.4366x; 1.4366x over previous
//
#include <hip/hip_runtime.h>
#include <hip/hip_bf16.h>

typedef __attribute__((ext_vector_type(8))) short bf16x8;
typedef __attribute__((ext_vector_type(4))) float f32x4;

#define NH 16
#define DM 1024
#define HD 64
#define CSEQ 2048
#define MROWS 8192   // B*C
#define NBH 64       // B*NH

static __device__ __forceinline__ unsigned short f2bf(float f) {
  __hip_bfloat16 h = __float2bfloat16(f);
  return *reinterpret_cast<unsigned short*>(&h);
}

static __device__ __forceinline__ short bf_qscale(short s) {
  // fold attn scale (1/8) and log2(e) into Q: S*0.125*1.4427 -> exp2 domain
  unsigned u = ((unsigned)(unsigned short)s) << 16;
  float f = __builtin_bit_cast(float, u) * 0.18033688f;
  return (short)f2bf(f);
}

static __device__ __forceinline__ void gload_lds16(const void* g, void* l) {
  __builtin_amdgcn_global_load_lds(
      (const __attribute__((address_space(1))) unsigned int*)g,
      (__attribute__((address_space(3))) unsigned int*)l, 16, 0, 0);
}

// ---------------- fused prep: x cast (blocks 0..2047), Wqkv^T (next 3072),
// Wo^T (next 1024).  One launch instead of three; per-block uniform branch. ----
__global__ __launch_bounds__(256) void prep(const float* __restrict__ x,
                                            const float* __restrict__ Wqkv,
                                            const float* __restrict__ Wo,
                                            unsigned short* __restrict__ xb,
                                            unsigned short* __restrict__ wqkvT,
                                            unsigned short* __restrict__ woT) {
  __shared__ float tile[32][33];
  int blk = blockIdx.x;
  if (blk < 2048) {
    // cast fp32 -> bf16, vectorized x4
    int n4 = (MROWS * DM) / 4;
    int stride = 2048 * 256;
    for (int i = blk * 256 + threadIdx.x; i < n4; i += stride) {
      float4 v = ((const float4*)x)[i];
      ushort4 o;
      o.x = f2bf(v.x); o.y = f2bf(v.y); o.z = f2bf(v.z); o.w = f2bf(v.w);
      ((ushort4*)xb)[i] = o;
    }
  } else {
    // transpose + cast: src[K][N] fp32 -> dst[N][K] bf16  (K = DM)
    int idx = blk - 2048;
    const float* src;
    unsigned short* dst;
    int N, bx, by;
    if (idx < 3072) { src = Wqkv; dst = wqkvT; N = 3 * DM; bx = idx % 96; by = idx / 96; }
    else { idx -= 3072; src = Wo; dst = woT; N = DM; bx = idx % 32; by = idx / 32; }
    int tx = threadIdx.x & 31, ty = threadIdx.x >> 5;   // 32 x 8
    int n0 = bx * 32, k0 = by * 32;
    #pragma unroll
    for (int i = 0; i < 32; i += 8)
      tile[ty + i][tx] = src[(size_t)(k0 + ty + i) * N + n0 + tx];
    __syncthreads();
    #pragma unroll
    for (int i = 0; i < 32; i += 8)
      dst[(size_t)(n0 + ty + i) * DM + k0 + tx] = f2bf(tile[tx][ty + i]);
  }
}

// ---------------- shared helpers ----------------
template<int CNT>
static __device__ __forceinline__ void ld_frags(const char* base, int r0, int cx, int g,
                                                bf16x8 (*out)[2]) {
  #pragma unroll
  for (int i = 0; i < CNT; i++) {
    int row = r0 + i * 16 + cx;
    #pragma unroll
    for (int kc = 0; kc < 2; kc++)
      out[i][kc] = *(const bf16x8*)(base + row * 128 + ((((kc << 2) | g) ^ (row & 7)) << 4));
  }
}

#define BARR() __builtin_amdgcn_s_barrier()
#define LGKM0() asm volatile("s_waitcnt lgkmcnt(0)" ::: "memory")
#define VMCNT8() asm volatile("s_waitcnt vmcnt(8)" ::: "memory")
#define VMCNT0() asm volatile("s_waitcnt vmcnt(0)" ::: "memory")
#define PRIO1() __builtin_amdgcn_s_setprio(1)
#define PRIO0() __builtin_amdgcn_s_setprio(0)

// ===================== 128x128 bf16 GEMM, 2 blocks/CU, 2 barriers/tile =====================
// R9-verified (83.7us QKV @ MfmaUtil 25%, best total 190.4us).
//   reads -> lgkm0 -> BARR (buffer dead) -> stage t+2 into it -> 32 MFMA
//   -> vmcnt(8) -> BARR.
// MODE 0: write fp32 out[M][N].
// MODE 1: scatter bf16 into Q,K [bh][cq][d]; V transposed+kappa-permuted.
static __device__ __forceinline__ void mfma_all(const bf16x8 af[4][2], const bf16x8 bfr[4][2],
                                                f32x4 acc[4][4]) {
  #pragma unroll
  for (int kc = 0; kc < 2; kc++)
    #pragma unroll
    for (int mi = 0; mi < 4; mi++)
      #pragma unroll
      for (int ni = 0; ni < 4; ni++)
        acc[mi][ni] = __builtin_amdgcn_mfma_f32_16x16x32_bf16(
            af[mi][kc], bfr[ni][kc], acc[mi][ni], 0, 0, 0);
}

template<int MODE>
__global__ __launch_bounds__(256, 2) void gemm128d(const unsigned short* __restrict__ A,
                                                   const unsigned short* __restrict__ BT,
                                                   const float* __restrict__ bias,
                                                   float* __restrict__ outF,
                                                   unsigned short* __restrict__ outQKV,
                                                   int N, int K) {
  __shared__ char sA[2][16384];   // [128 rows][64 k] bf16, rows 128B, slot^(row&7) swizzle
  __shared__ char sB[2][16384];
  int tid = threadIdx.x;
  int w = tid >> 6, l = tid & 63, g = l >> 4, cx = l & 15;
  int wm = (w >> 1) * 64, wn = (w & 1) * 64;

  // XCD-aware bijective swizzle (nwg % 8 == 0: 1536 and 512)
  int nwgx = gridDim.x;
  int nwg = nwgx * gridDim.y;
  int gid = blockIdx.y * nwgx + blockIdx.x;
  int swz = (gid & 7) * (nwg >> 3) + (gid >> 3);
  int bm = (swz / nwgx) * 128, bn = (swz % nwgx) * 128;

  const unsigned short* Ap[4];
  const unsigned short* Bp[4];
  #pragma unroll
  for (int i = 0; i < 4; i++) {
    int c = tid + i * 256;
    int ar = c >> 3, as = ((c & 7) ^ (ar & 7)) * 8;
    Ap[i] = A + (size_t)(bm + ar) * K + as;
    Bp[i] = BT + (size_t)(bn + ar) * K + as;
  }

  #define STAGE_AB(t, buf) do { int ko_ = (t) << 6;                 \
      gload_lds16(Ap[0] + ko_, sA[buf] + (tid)       * 16);         \
      gload_lds16(Ap[1] + ko_, sA[buf] + (tid + 256) * 16);         \
      gload_lds16(Ap[2] + ko_, sA[buf] + (tid + 512) * 16);         \
      gload_lds16(Ap[3] + ko_, sA[buf] + (tid + 768) * 16);         \
      gload_lds16(Bp[0] + ko_, sB[buf] + (tid)       * 16);         \
      gload_lds16(Bp[1] + ko_, sB[buf] + (tid + 256) * 16);         \
      gload_lds16(Bp[2] + ko_, sB[buf] + (tid + 512) * 16);         \
      gload_lds16(Bp[3] + ko_, sB[buf] + (tid + 768) * 16);         \
    } while (0)

  f32x4 acc[4][4];
  #pragma unroll
  for (int i = 0; i < 4; i++)
    #pragma unroll
    for (int j = 0; j < 4; j++) acc[i][j] = (f32x4){0.f, 0.f, 0.f, 0.f};

  int NT = K >> 6;

  // prologue: t0 -> buf0, t1 -> buf1 (t1's 8 stay in flight)
  STAGE_AB(0, 0);
  STAGE_AB(1, 1);
  VMCNT8();
  BARR();

  int cur = 0;
  for (int t = 0; t < NT; t++) {
    const char* Ac = sA[cur];
    const char* Bc = sB[cur];
    bool h1 = (t + 1) < NT, h2 = (t + 2) < NT;
    bf16x8 af[4][2], bfr[4][2];

    // all 16 frag reads, then wait them into registers
    ld_frags<4>(Ac, wm, cx, g, af);
    ld_frags<4>(Bc, wn, cx, g, bfr);
    LGKM0();
    BARR();   // every wave's frags now in regs -> buffer cur is dead

    // stage t+2 into the dead buffer; full-tile window to its vmcnt deadline
    if (h2) STAGE_AB(t + 2, cur);

    PRIO1(); mfma_all(af, bfr, acc); PRIO0();

    if (h2)      { VMCNT8(); }   // t+1's 8 landed; t+2's 8 stay in flight
    else if (h1) { VMCNT0(); }   // final boundary only
    BARR();
    cur ^= 1;
  }

  // epilogue: C/D layout row=(l>>4)*4+r (m-side), col=l&15 (n-side)
  #pragma unroll
  for (int mi = 0; mi < 4; mi++) {
    #pragma unroll
    for (int ni = 0; ni < 4; ni++) {
      int col = bn + wn + ni * 16 + cx;
      float bv = bias[col];
      int row0 = bm + wm + mi * 16 + g * 4;
      #pragma unroll
      for (int r = 0; r < 4; r++) {
        float v = acc[mi][ni][r] + bv;
        int rr = row0 + r;
        if (MODE == 0) {
          outF[(size_t)rr * N + col] = v;
        } else {
          int which = col >> 10, rem = col & 1023;
          int h = rem >> 6, d = rem & 63;
          int b = rr >> 11, cq = rr & 2047;
          if (which == 2) {
            // V: store transposed + kappa-permuted (pure within-32 permutation)
            int pos = (cq & ~31) + (((cq >> 2) & 3) << 3) + (((cq >> 4) & 1) << 2) + (cq & 3);
            outQKV[((size_t)2 * NBH + b * NH + h) * (CSEQ * HD) +
                   (size_t)d * CSEQ + pos] = f2bf(v);
          } else {
            outQKV[((size_t)which * NBH + b * NH + h) * (CSEQ * HD) + (size_t)cq * HD + d] = f2bf(v);
          }
        }
      }
    }
  }
  #undef STAGE_AB
}

// ---------------- flash attention (causal), swapped-QK^T, register-P ----------------
// R9-verified: 8 waves x 16 q-rows (QBLK=128), KVBLK=128, dbuf, one barrier/iter,
// XCD-aware remap, exp2 softmax, defer-max, DMA staging, ones-MFMA denominator
// (osum accumulates P*1 in O's D-layout; rescale alpha applies to osum too).
__global__ __launch_bounds__(512, 4) void attn_kernel(const unsigned short* __restrict__ Qb,
                                                      const unsigned short* __restrict__ Kb,
                                                      const unsigned short* __restrict__ VTb,
                                                      unsigned short* __restrict__ O) {
  __shared__ char sKb[2][16384]; // K [128 k][64 d] bf16: slot sp of row holds d-slot sp^(row&7)
  __shared__ char sVt[2][16384]; // V^T [64 d][128 pos] bf16: slot sp of row d holds pos-slot sp^(d&7)
  int tid = threadIdx.x;
  int w = tid >> 6, l = tid & 63, g = l >> 4, cx = l & 15;
  int gid = blockIdx.x;
  int bh = ((gid >> 7) << 3) | (gid & 7);
  int qt = 15 - ((gid >> 3) & 15);

  const unsigned short* Qp  = Qb  + (size_t)bh * CSEQ * HD;
  const unsigned short* Kp  = Kb  + (size_t)bh * CSEQ * HD;
  const unsigned short* VTp = VTb + (size_t)bh * CSEQ * HD;  // [64 d][2048 k']

  int qrow = qt * 128 + w * 16 + cx;
  bf16x8 qf[2];
  qf[0] = *(const bf16x8*)(Qp + (size_t)qrow * HD + g * 8);
  qf[1] = *(const bf16x8*)(Qp + (size_t)qrow * HD + 32 + g * 8);
  #pragma unroll
  for (int kc = 0; kc < 2; kc++)
    #pragma unroll
    for (int j = 0; j < 8; j++) qf[kc][j] = bf_qscale(qf[kc][j]);

  bf16x8 vones;
  #pragma unroll
  for (int j = 0; j < 8; j++) vones[j] = (short)0x3F80;   // bf16 1.0

  f32x4 o[4], osum;
  #pragma unroll
  for (int nf2 = 0; nf2 < 4; nf2++) o[nf2] = (f32x4){0.f, 0.f, 0.f, 0.f};
  osum = (f32x4){0.f, 0.f, 0.f, 0.f};
  float mrow = -INFINITY;

  int c0 = tid, c1 = tid + 512;
  int krow0 = c0 >> 3, ksl0 = (c0 & 7) ^ (krow0 & 7);
  int krow1 = c1 >> 3, ksl1 = (c1 & 7) ^ (krow1 & 7);
  int vd0 = c0 >> 4, vsl0 = (c0 & 15) ^ (vd0 & 7);
  int vd1 = c1 >> 4, vsl1 = (c1 & 15) ^ (vd1 & 7);
  const unsigned short* Ksrc0 = Kp + (size_t)krow0 * HD + ksl0 * 8;   // += kt*8192
  const unsigned short* Ksrc1 = Kp + (size_t)krow1 * HD + ksl1 * 8;
  const unsigned short* Vsrc0 = VTp + (size_t)vd0 * CSEQ + vsl0 * 8;  // += kt*128
  const unsigned short* Vsrc1 = VTp + (size_t)vd1 * CSEQ + vsl1 * 8;

  gload_lds16(Ksrc0, sKb[0] + c0 * 16);
  gload_lds16(Ksrc1, sKb[0] + c1 * 16);
  gload_lds16(Vsrc0, sVt[0] + c0 * 16);
  gload_lds16(Vsrc1, sVt[0] + c1 * 16);
  __syncthreads();
  int cur = 0;

  for (int kt = 0; kt <= qt; kt++) {
    if (kt < qt) {
      size_t ko = (size_t)(kt + 1) * 128 * HD;
      size_t vo = (size_t)(kt + 1) * 128;
      gload_lds16(Ksrc0 + ko, sKb[cur ^ 1] + c0 * 16);
      gload_lds16(Ksrc1 + ko, sKb[cur ^ 1] + c1 * 16);
      gload_lds16(Vsrc0 + vo, sVt[cur ^ 1] + c0 * 16);
      gload_lds16(Vsrc1 + vo, sVt[cur ^ 1] + c1 * 16);
    }
    const char* Kc = sKb[cur];
    const char* Vc = sVt[cur];

    f32x4 sacc[8];
    #pragma unroll
    for (int nf = 0; nf < 8; nf++) sacc[nf] = (f32x4){0.f, 0.f, 0.f, 0.f};
    __builtin_amdgcn_s_setprio(1);
    #pragma unroll
    for (int kc = 0; kc < 2; kc++) {
      #pragma unroll
      for (int nf = 0; nf < 8; nf++) {
        int row = nf * 16 + cx;
        bf16x8 kf = *(const bf16x8*)(Kc + row * 128 + ((((kc << 2) | g) ^ (row & 7)) << 4));
        sacc[nf] = __builtin_amdgcn_mfma_f32_16x16x32_bf16(kf, qf[kc], sacc[nf], 0, 0, 0);
      }
    }
    __builtin_amdgcn_s_setprio(0);

    if (kt == qt) {
      #pragma unroll
      for (int nf = 0; nf < 8; nf++)
        #pragma unroll
        for (int r = 0; r < 4; r++)
          if (nf * 16 + 4 * g + r > w * 16 + cx) sacc[nf][r] = -INFINITY;
    }
    float m8[8];
    #pragma unroll
    for (int nf = 0; nf < 8; nf++)
      m8[nf] = fmaxf(fmaxf(sacc[nf][0], sacc[nf][1]), fmaxf(sacc[nf][2], sacc[nf][3]));
    float mx = fmaxf(fmaxf(fmaxf(m8[0], m8[1]), fmaxf(m8[2], m8[3])),
                     fmaxf(fmaxf(m8[4], m8[5]), fmaxf(m8[6], m8[7])));
    mx = fmaxf(mx, __shfl_xor(mx, 16));
    mx = fmaxf(mx, __shfl_xor(mx, 32));

    if (!__all(mx - mrow <= 8.f)) {
      float mnew = fmaxf(mrow, mx);
      float alpha = __builtin_amdgcn_exp2f(mrow - mnew);
      mrow = mnew;
      #pragma unroll
      for (int r = 0; r < 4; r++) {
        float ar = __shfl(alpha, (l & 48) | ((l >> 2) & 12) | r);
        #pragma unroll
        for (int nf2 = 0; nf2 < 4; nf2++) o[nf2][r] *= ar;
        osum[r] *= ar;
      }
    }
    #pragma unroll
    for (int nf = 0; nf < 8; nf++)
      #pragma unroll
      for (int r = 0; r < 4; r++)
        sacc[nf][r] = __builtin_amdgcn_exp2f(sacc[nf][r] - mrow);

    bf16x8 pa[4];
    #pragma unroll
    for (int kc = 0; kc < 4; kc++) {
      #pragma unroll
      for (int j = 0; j < 4; j++) {
        pa[kc][j]     = (short)f2bf(sacc[2 * kc][j]);
        pa[kc][j + 4] = (short)f2bf(sacc[2 * kc + 1][j]);
      }
    }

    __builtin_amdgcn_s_setprio(1);
    #pragma unroll
    for (int kc = 0; kc < 4; kc++) {
      #pragma unroll
      for (int nf2 = 0; nf2 < 4; nf2++) {
        int d = nf2 * 16 + cx;
        bf16x8 vf = *(const bf16x8*)(Vc + ((d * 256 + (((kc << 2) | g) << 4)) ^ ((d & 7) << 4)));
        o[nf2] = __builtin_amdgcn_mfma_f32_16x16x32_bf16(pa[kc], vf, o[nf2], 0, 0, 0);
      }
      osum = __builtin_amdgcn_mfma_f32_16x16x32_bf16(pa[kc], vones, osum, 0, 0, 0);
    }
    __builtin_amdgcn_s_setprio(0);

    if (kt < qt) {
      __syncthreads();
      cur ^= 1;
    }
  }

  int b = bh >> 4, h = bh & 15;
  #pragma unroll
  for (int r = 0; r < 4; r++) {
    float inv = 1.0f / osum[r];
    int q = qt * 128 + w * 16 + 4 * g + r;
    size_t base = ((size_t)(b * CSEQ + q)) * DM + h * HD;
    #pragma unroll
    for (int nf2 = 0; nf2 < 4; nf2++)
      O[base + nf2 * 16 + cx] = f2bf(o[nf2][r] * inv);
  }
}

// ---------------- launch ----------------
extern "C" void kernel_launch(void* const* d_in, const int* in_sizes, int n_in,
                              void* d_out, int out_size, void* d_ws, size_t ws_size,
                              hipStream_t stream) {
  const float* x    = (const float*)d_in[0];
  const float* Wqkv = (const float*)d_in[1];
  const float* bqkv = (const float*)d_in[2];
  const float* Wo   = (const float*)d_in[3];
  const float* bo   = (const float*)d_in[4];
  float* out = (float*)d_out;

  unsigned short* ws = (unsigned short*)d_ws;
  const size_t XB_OFF    = 0;                     // x bf16 [8192][1024]
  const size_t WQKVT_OFF = 8388608;               // Wqkv^T bf16 [3072][1024]
  const size_t WOT_OFF   = WQKVT_OFF + 3145728;   // Wo^T bf16 [1024][1024]
  const size_t QKV_OFF   = WOT_OFF + 1048576;     // Q,K [bh][k][d]; V^T [bh][d][k']
  const size_t ATT_OFF   = QKV_OFF + 3 * 8388608; // att out bf16 [8192][1024]

  unsigned short* xb    = ws + XB_OFF;
  unsigned short* wqkvT = ws + WQKVT_OFF;
  unsigned short* woT   = ws + WOT_OFF;
  unsigned short* qkv   = ws + QKV_OFF;
  unsigned short* att   = ws + ATT_OFF;

  // fused pre-pass: 2048 cast blocks + 3072 Wqkv-transpose + 1024 Wo-transpose
  prep<<<dim3(6144), 256, 0, stream>>>(x, Wqkv, Wo, xb, wqkvT, woT);

  // 128x128 tile, 2 blocks/CU: QKV 24x64 = 1536 blocks (3 rounds of 512),
  // proj 8x64 = 512 blocks (1 exact round)
  gemm128d<1><<<dim3(3 * DM / 128, MROWS / 128), 256, 0, stream>>>(
      xb, wqkvT, bqkv, nullptr, qkv, 3 * DM, DM);

  attn_kernel<<<dim3(1024), 512, 0, stream>>>(
      qkv, qkv + 8388608, qkv + 16777216, att);

  gemm128d<0><<<dim3(DM / 128, MROWS / 128), 256, 0, stream>>>(
      att, woT, bo, out, nullptr, DM, DM);
}

// Round 13
// 185.792 us; speedup vs baseline: 1.4430x; 1.0045x over previous
//
#include <hip/hip_runtime.h>
#include <hip/hip_bf16.h>

typedef __attribute__((ext_vector_type(8))) short bf16x8;
typedef __attribute__((ext_vector_type(4))) float f32x4;

#define NH 16
#define DM 1024
#define HD 64
#define CSEQ 2048
#define MROWS 8192   // B*C
#define NBH 64       // B*NH

static __device__ __forceinline__ unsigned short f2bf(float f) {
  __hip_bfloat16 h = __float2bfloat16(f);
  return *reinterpret_cast<unsigned short*>(&h);
}

static __device__ __forceinline__ short bf_qscale(short s) {
  // fold attn scale (1/8) and log2(e) into Q: S*0.125*1.4427 -> exp2 domain
  unsigned u = ((unsigned)(unsigned short)s) << 16;
  float f = __builtin_bit_cast(float, u) * 0.18033688f;
  return (short)f2bf(f);
}

static __device__ __forceinline__ void gload_lds16(const void* g, void* l) {
  __builtin_amdgcn_global_load_lds(
      (const __attribute__((address_space(1))) unsigned int*)g,
      (__attribute__((address_space(3))) unsigned int*)l, 16, 0, 0);
}

// ---------------- fused prep: x cast (blocks 0..2047), Wqkv^T (next 3072),
// Wo^T (next 1024).  One launch instead of three (R12-verified). ----
__global__ __launch_bounds__(256) void prep(const float* __restrict__ x,
                                            const float* __restrict__ Wqkv,
                                            const float* __restrict__ Wo,
                                            unsigned short* __restrict__ xb,
                                            unsigned short* __restrict__ wqkvT,
                                            unsigned short* __restrict__ woT) {
  __shared__ float tile[32][33];
  int blk = blockIdx.x;
  if (blk < 2048) {
    int n4 = (MROWS * DM) / 4;
    int stride = 2048 * 256;
    for (int i = blk * 256 + threadIdx.x; i < n4; i += stride) {
      float4 v = ((const float4*)x)[i];
      ushort4 o;
      o.x = f2bf(v.x); o.y = f2bf(v.y); o.z = f2bf(v.z); o.w = f2bf(v.w);
      ((ushort4*)xb)[i] = o;
    }
  } else {
    int idx = blk - 2048;
    const float* src;
    unsigned short* dst;
    int N, bx, by;
    if (idx < 3072) { src = Wqkv; dst = wqkvT; N = 3 * DM; bx = idx % 96; by = idx / 96; }
    else { idx -= 3072; src = Wo; dst = woT; N = DM; bx = idx % 32; by = idx / 32; }
    int tx = threadIdx.x & 31, ty = threadIdx.x >> 5;   // 32 x 8
    int n0 = bx * 32, k0 = by * 32;
    #pragma unroll
    for (int i = 0; i < 32; i += 8)
      tile[ty + i][tx] = src[(size_t)(k0 + ty + i) * N + n0 + tx];
    __syncthreads();
    #pragma unroll
    for (int i = 0; i < 32; i += 8)
      dst[(size_t)(n0 + ty + i) * DM + k0 + tx] = f2bf(tile[tx][ty + i]);
  }
}

// ---------------- shared helpers ----------------
template<int CNT>
static __device__ __forceinline__ void ld_frags(const char* base, int r0, int cx, int g,
                                                bf16x8 (*out)[2]) {
  #pragma unroll
  for (int i = 0; i < CNT; i++) {
    int row = r0 + i * 16 + cx;
    #pragma unroll
    for (int kc = 0; kc < 2; kc++)
      out[i][kc] = *(const bf16x8*)(base + row * 128 + ((((kc << 2) | g) ^ (row & 7)) << 4));
  }
}

#define BARR() __builtin_amdgcn_s_barrier()
#define LGKM0() asm volatile("s_waitcnt lgkmcnt(0)" ::: "memory")
#define VMCNT8() asm volatile("s_waitcnt vmcnt(8)" ::: "memory")
#define VMCNT0() asm volatile("s_waitcnt vmcnt(0)" ::: "memory")
#define PRIO1() __builtin_amdgcn_s_setprio(1)
#define PRIO0() __builtin_amdgcn_s_setprio(0)

// ===================== 128x128 bf16 GEMM, 2 blocks/CU, 2 barriers/tile =====================
// R9/R12-verified (83 us QKV @ MfmaUtil 25%).
//   reads -> lgkm0 -> BARR (buffer dead) -> stage t+2 into it -> 32 MFMA
//   -> vmcnt(8) -> BARR.
// MODE 0: write fp32 out[M][N].
// MODE 1: scatter bf16 into Q,K [bh][cq][d]; V transposed+kappa-permuted.
static __device__ __forceinline__ void mfma_all(const bf16x8 af[4][2], const bf16x8 bfr[4][2],
                                                f32x4 acc[4][4]) {
  #pragma unroll
  for (int kc = 0; kc < 2; kc++)
    #pragma unroll
    for (int mi = 0; mi < 4; mi++)
      #pragma unroll
      for (int ni = 0; ni < 4; ni++)
        acc[mi][ni] = __builtin_amdgcn_mfma_f32_16x16x32_bf16(
            af[mi][kc], bfr[ni][kc], acc[mi][ni], 0, 0, 0);
}

template<int MODE>
__global__ __launch_bounds__(256, 2) void gemm128d(const unsigned short* __restrict__ A,
                                                   const unsigned short* __restrict__ BT,
                                                   const float* __restrict__ bias,
                                                   float* __restrict__ outF,
                                                   unsigned short* __restrict__ outQKV,
                                                   int N, int K) {
  __shared__ char sA[2][16384];   // [128 rows][64 k] bf16, rows 128B, slot^(row&7) swizzle
  __shared__ char sB[2][16384];
  int tid = threadIdx.x;
  int w = tid >> 6, l = tid & 63, g = l >> 4, cx = l & 15;
  int wm = (w >> 1) * 64, wn = (w & 1) * 64;

  // XCD-aware bijective swizzle (nwg % 8 == 0: 1536 and 512)
  int nwgx = gridDim.x;
  int nwg = nwgx * gridDim.y;
  int gid = blockIdx.y * nwgx + blockIdx.x;
  int swz = (gid & 7) * (nwg >> 3) + (gid >> 3);
  int bm = (swz / nwgx) * 128, bn = (swz % nwgx) * 128;

  const unsigned short* Ap[4];
  const unsigned short* Bp[4];
  #pragma unroll
  for (int i = 0; i < 4; i++) {
    int c = tid + i * 256;
    int ar = c >> 3, as = ((c & 7) ^ (ar & 7)) * 8;
    Ap[i] = A + (size_t)(bm + ar) * K + as;
    Bp[i] = BT + (size_t)(bn + ar) * K + as;
  }

  #define STAGE_AB(t, buf) do { int ko_ = (t) << 6;                 \
      gload_lds16(Ap[0] + ko_, sA[buf] + (tid)       * 16);         \
      gload_lds16(Ap[1] + ko_, sA[buf] + (tid + 256) * 16);         \
      gload_lds16(Ap[2] + ko_, sA[buf] + (tid + 512) * 16);         \
      gload_lds16(Ap[3] + ko_, sA[buf] + (tid + 768) * 16);         \
      gload_lds16(Bp[0] + ko_, sB[buf] + (tid)       * 16);         \
      gload_lds16(Bp[1] + ko_, sB[buf] + (tid + 256) * 16);         \
      gload_lds16(Bp[2] + ko_, sB[buf] + (tid + 512) * 16);         \
      gload_lds16(Bp[3] + ko_, sB[buf] + (tid + 768) * 16);         \
    } while (0)

  f32x4 acc[4][4];
  #pragma unroll
  for (int i = 0; i < 4; i++)
    #pragma unroll
    for (int j = 0; j < 4; j++) acc[i][j] = (f32x4){0.f, 0.f, 0.f, 0.f};

  int NT = K >> 6;

  STAGE_AB(0, 0);
  STAGE_AB(1, 1);
  VMCNT8();
  BARR();

  int cur = 0;
  for (int t = 0; t < NT; t++) {
    const char* Ac = sA[cur];
    const char* Bc = sB[cur];
    bool h1 = (t + 1) < NT, h2 = (t + 2) < NT;
    bf16x8 af[4][2], bfr[4][2];

    ld_frags<4>(Ac, wm, cx, g, af);
    ld_frags<4>(Bc, wn, cx, g, bfr);
    LGKM0();
    BARR();   // every wave's frags now in regs -> buffer cur is dead

    if (h2) STAGE_AB(t + 2, cur);

    PRIO1(); mfma_all(af, bfr, acc); PRIO0();

    if (h2)      { VMCNT8(); }
    else if (h1) { VMCNT0(); }
    BARR();
    cur ^= 1;
  }

  #pragma unroll
  for (int mi = 0; mi < 4; mi++) {
    #pragma unroll
    for (int ni = 0; ni < 4; ni++) {
      int col = bn + wn + ni * 16 + cx;
      float bv = bias[col];
      int row0 = bm + wm + mi * 16 + g * 4;
      #pragma unroll
      for (int r = 0; r < 4; r++) {
        float v = acc[mi][ni][r] + bv;
        int rr = row0 + r;
        if (MODE == 0) {
          outF[(size_t)rr * N + col] = v;
        } else {
          int which = col >> 10, rem = col & 1023;
          int h = rem >> 6, d = rem & 63;
          int b = rr >> 11, cq = rr & 2047;
          if (which == 2) {
            // V: store transposed + kappa-permuted (pure within-32 permutation)
            int pos = (cq & ~31) + (((cq >> 2) & 3) << 3) + (((cq >> 4) & 1) << 2) + (cq & 3);
            outQKV[((size_t)2 * NBH + b * NH + h) * (CSEQ * HD) +
                   (size_t)d * CSEQ + pos] = f2bf(v);
          } else {
            outQKV[((size_t)which * NBH + b * NH + h) * (CSEQ * HD) + (size_t)cq * HD + d] = f2bf(v);
          }
        }
      }
    }
  }
  #undef STAGE_AB
}

// ---------------- flash attention (causal), KVBLK=64, 2x q-reuse ----------------
// 4 waves x 32 q-rows (QBLK=128, grid 1024 as R12), KVBLK=64.  K/V LDS frags
// are shared across the two q-halves: each kf/vf ds_read_b128 feeds 2 MFMAs
// -> LDS read traffic HALVED vs R12 (128 vs 256 b128 per block per 128 kv).
// LDS 32KB (2 x (8KB K + 8KB V)) + ~110 VGPR @ launch_bounds(256,2) (R5-safe
// cap) -> 4-5 blocks/CU = 16-20 waves/CU (R5's failure was 8; occupancy now
// restored).  Same per-(q,kv) MFMA/VALU work as R12; kappa perm is within-32
// so producer unchanged; ones-MFMA denominator per q-half; defer-max; dbuf;
// one barrier/tile; R12 decode/LPT.
__global__ __launch_bounds__(256, 2) void attn_kernel(const unsigned short* __restrict__ Qb,
                                                      const unsigned short* __restrict__ Kb,
                                                      const unsigned short* __restrict__ VTb,
                                                      unsigned short* __restrict__ O) {
  __shared__ char sKb[2][8192]; // K tile [64 kv][64 d]: slot sp of row holds d-slot sp^(row&7)
  __shared__ char sVt[2][8192]; // V^T tile [64 d][64 kv]: slot sp of row d holds kv-slot sp^(d&7)
  int tid = threadIdx.x;
  int w = tid >> 6, l = tid & 63, g = l >> 4, cx = l & 15;   // w in 0..3
  int gid = blockIdx.x;
  int bh = ((gid >> 7) << 3) | (gid & 7);
  int qt = 15 - ((gid >> 3) & 15);
  int NKV = 2 * qt + 2;    // 64-kv tiles

  const unsigned short* Qp  = Qb  + (size_t)bh * CSEQ * HD;
  const unsigned short* Kp  = Kb  + (size_t)bh * CSEQ * HD;
  const unsigned short* VTp = VTb + (size_t)bh * CSEQ * HD;  // [64 d][2048 kv]

  // Q fragments, two q-halves per wave (B-operand: col=lane&15=q, k=g*8+j)
  bf16x8 qf[2][2];
  #pragma unroll
  for (int qh = 0; qh < 2; qh++) {
    int qrow = qt * 128 + w * 32 + qh * 16 + cx;
    qf[qh][0] = *(const bf16x8*)(Qp + (size_t)qrow * HD + g * 8);
    qf[qh][1] = *(const bf16x8*)(Qp + (size_t)qrow * HD + 32 + g * 8);
    #pragma unroll
    for (int kc = 0; kc < 2; kc++)
      #pragma unroll
      for (int j = 0; j < 8; j++) qf[qh][kc][j] = bf_qscale(qf[qh][kc][j]);
  }

  bf16x8 vones;
  #pragma unroll
  for (int j = 0; j < 8; j++) vones[j] = (short)0x3F80;   // bf16 1.0

  f32x4 o[2][4], osum[2];
  #pragma unroll
  for (int qh = 0; qh < 2; qh++) {
    #pragma unroll
    for (int nf2 = 0; nf2 < 4; nf2++) o[qh][nf2] = (f32x4){0.f, 0.f, 0.f, 0.f};
    osum[qh] = (f32x4){0.f, 0.f, 0.f, 0.f};
  }
  float mrow[2] = {-INFINITY, -INFINITY};

  // staging: tile = 512 chunks of 16B for each of K and V; 256 thr -> 2 chunks each
  const unsigned short* Ks[2];
  const unsigned short* Vs[2];
  #pragma unroll
  for (int i = 0; i < 2; i++) {
    int c = tid + i * 256;
    int r = c >> 3, sl = (c & 7) ^ (r & 7);
    Ks[i] = Kp + (size_t)r * HD + sl * 8;     // += kt*64*HD
    Vs[i] = VTp + (size_t)r * CSEQ + sl * 8;  // += kt*64
  }

  #define ATT_STAGE(ko, vo, buf) do {                                    \
      gload_lds16(Ks[0] + (ko), sKb[buf] + (tid)       * 16);            \
      gload_lds16(Ks[1] + (ko), sKb[buf] + (tid + 256) * 16);            \
      gload_lds16(Vs[0] + (vo), sVt[buf] + (tid)       * 16);            \
      gload_lds16(Vs[1] + (vo), sVt[buf] + (tid + 256) * 16);            \
    } while (0)

  ATT_STAGE((size_t)0, (size_t)0, 0);
  __syncthreads();
  int cur = 0;

  for (int kt = 0; kt < NKV; kt++) {
    if (kt + 1 < NKV) {  // DMA next tile into buf^1; lands under compute below
      ATT_STAGE((size_t)(kt + 1) * 64 * HD, (size_t)(kt + 1) * 64, cur ^ 1);
    }
    const char* Kc = sKb[cur];
    const char* Vc = sVt[cur];

    // ---- S^T = K * Q^T over 64 kv: each kf read feeds BOTH q-halves ----
    f32x4 sacc[2][4];
    #pragma unroll
    for (int qh = 0; qh < 2; qh++)
      #pragma unroll
      for (int nf = 0; nf < 4; nf++) sacc[qh][nf] = (f32x4){0.f, 0.f, 0.f, 0.f};
    PRIO1();
    #pragma unroll
    for (int kc = 0; kc < 2; kc++) {
      #pragma unroll
      for (int nf = 0; nf < 4; nf++) {
        int row = nf * 16 + cx;
        bf16x8 kf = *(const bf16x8*)(Kc + row * 128 + ((((kc << 2) | g) ^ (row & 7)) << 4));
        sacc[0][nf] = __builtin_amdgcn_mfma_f32_16x16x32_bf16(kf, qf[0][kc], sacc[0][nf], 0, 0, 0);
        sacc[1][nf] = __builtin_amdgcn_mfma_f32_16x16x32_bf16(kf, qf[1][kc], sacc[1][nf], 0, 0, 0);
      }
    }
    PRIO0();

    // lane (g,cx), half qh holds S[q = w*32+qh*16+cx][kv = kt*64 + nf*16+4g+r]
    if (kt >= NKV - 2) {  // only the last two kv-tiles can touch the diagonal
      #pragma unroll
      for (int qh = 0; qh < 2; qh++) {
        int qglob = qt * 128 + w * 32 + qh * 16 + cx;
        #pragma unroll
        for (int nf = 0; nf < 4; nf++)
          #pragma unroll
          for (int r = 0; r < 4; r++)
            if (kt * 64 + nf * 16 + 4 * g + r > qglob) sacc[qh][nf][r] = -INFINITY;
      }
    }
    // per-half tree max + cross-lane reduce (q owned by cx across g/hi)
    float mx[2];
    #pragma unroll
    for (int qh = 0; qh < 2; qh++) {
      float m4[4];
      #pragma unroll
      for (int nf = 0; nf < 4; nf++)
        m4[nf] = fmaxf(fmaxf(sacc[qh][nf][0], sacc[qh][nf][1]), fmaxf(sacc[qh][nf][2], sacc[qh][nf][3]));
      float m = fmaxf(fmaxf(m4[0], m4[1]), fmaxf(m4[2], m4[3]));
      m = fmaxf(m, __shfl_xor(m, 16));
      m = fmaxf(m, __shfl_xor(m, 32));
      mx[qh] = m;
    }

    // defer-max (T13): shared decision across both halves
    float need = fmaxf(mx[0] - mrow[0], mx[1] - mrow[1]);
    if (!__all(need <= 8.f)) {
      #pragma unroll
      for (int qh = 0; qh < 2; qh++) {
        float mnew = fmaxf(mrow[qh], mx[qh]);
        float alpha = __builtin_amdgcn_exp2f(mrow[qh] - mnew);
        mrow[qh] = mnew;
        #pragma unroll
        for (int r = 0; r < 4; r++) {
          float ar = __shfl(alpha, (l & 48) | ((l >> 2) & 12) | r);
          #pragma unroll
          for (int nf2 = 0; nf2 < 4; nf2++) o[qh][nf2][r] *= ar;
          osum[qh][r] *= ar;
        }
      }
    }
    #pragma unroll
    for (int qh = 0; qh < 2; qh++)
      #pragma unroll
      for (int nf = 0; nf < 4; nf++)
        #pragma unroll
        for (int r = 0; r < 4; r++)
          sacc[qh][nf][r] = __builtin_amdgcn_exp2f(sacc[qh][nf][r] - mrow[qh]);

    // P -> bf16 A-frags; kc=0..1: elem j carries kv = 32kc + 16*(j>=4) + 4g + (j&3)
    bf16x8 pa[2][2];
    #pragma unroll
    for (int qh = 0; qh < 2; qh++)
      #pragma unroll
      for (int kc = 0; kc < 2; kc++) {
        #pragma unroll
        for (int j = 0; j < 4; j++) {
          pa[qh][kc][j]     = (short)f2bf(sacc[qh][2 * kc][j]);
          pa[qh][kc][j + 4] = (short)f2bf(sacc[qh][2 * kc + 1][j]);
        }
      }

    // ---- O += P * V (each vf feeds both halves); osum += P * ones ----
    PRIO1();
    #pragma unroll
    for (int kc = 0; kc < 2; kc++) {
      #pragma unroll
      for (int nf2 = 0; nf2 < 4; nf2++) {
        int d = nf2 * 16 + cx;
        bf16x8 vf = *(const bf16x8*)(Vc + ((d * 128 + (((kc << 2) | g) << 4)) ^ ((d & 7) << 4)));
        o[0][nf2] = __builtin_amdgcn_mfma_f32_16x16x32_bf16(pa[0][kc], vf, o[0][nf2], 0, 0, 0);
        o[1][nf2] = __builtin_amdgcn_mfma_f32_16x16x32_bf16(pa[1][kc], vf, o[1][nf2], 0, 0, 0);
      }
      osum[0] = __builtin_amdgcn_mfma_f32_16x16x32_bf16(pa[0][kc], vones, osum[0], 0, 0, 0);
      osum[1] = __builtin_amdgcn_mfma_f32_16x16x32_bf16(pa[1][kc], vones, osum[1], 0, 0, 0);
    }
    PRIO0();

    if (kt + 1 < NKV) {   // single barrier per tile: drains DMAs + LDS reads
      __syncthreads();
      cur ^= 1;
    }
  }

  // epilogue: per half qh, lane (g,cx): O rows q = 4g+r, cols d = nf2*16+cx;
  // osum[qh][r] is the matching row's denominator (no shfl needed)
  int b = bh >> 4, hh = bh & 15;
  #pragma unroll
  for (int qh = 0; qh < 2; qh++) {
    #pragma unroll
    for (int r = 0; r < 4; r++) {
      float inv = 1.0f / osum[qh][r];
      int q = qt * 128 + w * 32 + qh * 16 + 4 * g + r;
      size_t base = ((size_t)(b * CSEQ + q)) * DM + hh * HD;
      #pragma unroll
      for (int nf2 = 0; nf2 < 4; nf2++)
        O[base + nf2 * 16 + cx] = f2bf(o[qh][nf2][r] * inv);
    }
  }
  #undef ATT_STAGE
}

// ---------------- launch ----------------
extern "C" void kernel_launch(void* const* d_in, const int* in_sizes, int n_in,
                              void* d_out, int out_size, void* d_ws, size_t ws_size,
                              hipStream_t stream) {
  const float* x    = (const float*)d_in[0];
  const float* Wqkv = (const float*)d_in[1];
  const float* bqkv = (const float*)d_in[2];
  const float* Wo   = (const float*)d_in[3];
  const float* bo   = (const float*)d_in[4];
  float* out = (float*)d_out;

  unsigned short* ws = (unsigned short*)d_ws;
  const size_t XB_OFF    = 0;                     // x bf16 [8192][1024]
  const size_t WQKVT_OFF = 8388608;               // Wqkv^T bf16 [3072][1024]
  const size_t WOT_OFF   = WQKVT_OFF + 3145728;   // Wo^T bf16 [1024][1024]
  const size_t QKV_OFF   = WOT_OFF + 1048576;     // Q,K [bh][k][d]; V^T [bh][d][k']
  const size_t ATT_OFF   = QKV_OFF + 3 * 8388608; // att out bf16 [8192][1024]

  unsigned short* xb    = ws + XB_OFF;
  unsigned short* wqkvT = ws + WQKVT_OFF;
  unsigned short* woT   = ws + WOT_OFF;
  unsigned short* qkv   = ws + QKV_OFF;
  unsigned short* att   = ws + ATT_OFF;

  // fused pre-pass: 2048 cast blocks + 3072 Wqkv-transpose + 1024 Wo-transpose
  prep<<<dim3(6144), 256, 0, stream>>>(x, Wqkv, Wo, xb, wqkvT, woT);

  // 128x128 tile, 2 blocks/CU: QKV 24x64 = 1536 blocks (3 rounds of 512),
  // proj 8x64 = 512 blocks (1 exact round)
  gemm128d<1><<<dim3(3 * DM / 128, MROWS / 128), 256, 0, stream>>>(
      xb, wqkvT, bqkv, nullptr, qkv, 3 * DM, DM);

  // KVBLK=64, q-reuse: 1024 blocks of 256 threads, 4-5 blocks/CU
  attn_kernel<<<dim3(1024), 256, 0, stream>>>(
      qkv, qkv + 8388608, qkv + 16777216, att);

  gemm128d<0><<<dim3(DM / 128, MROWS / 128), 256, 0, stream>>>(
      att, woT, bo, out, nullptr, DM, DM);
}